// Round 12
// baseline (107.218 us; speedup 1.0000x reference)
//
#include <hip/hip_runtime.h>

// GAT layer fused, MI355X gfx950 — v11 (resubmit after infra failure):
// swapped-QK^T flash (P lane-local -> PV A-frag built in registers, no sP
// LDS round-trip; permuted hnV k-order), int4 adj masks, conv fused into
// hnew. Pipeline: memset -> prep_k (count|packW) -> hnew_k -> attn_k -> comb_k.

typedef __attribute__((ext_vector_type(8))) short short8;   // 8 x bf16 (4 VGPR)
typedef __attribute__((ext_vector_type(4))) float f32x4;    // MFMA C/D frag

#define NN 8192
#define DD 256
#define NEGB -1.2983e16f  // -9e15 * log2(e): NEG_BIG in base-2 softmax domain

__device__ __forceinline__ unsigned short f2bf(float f) {
  unsigned u = __builtin_bit_cast(unsigned, f);
  u += 0x7FFFu + ((u >> 16) & 1u);  // RNE
  return (unsigned short)(u >> 16);
}
__device__ __forceinline__ float bf2f(unsigned short s) {
  unsigned u = ((unsigned)s) << 16;
  return __builtin_bit_cast(float, u);
}
__device__ __forceinline__ f32x4 mfma16(short8 a, short8 b, f32x4 c) {
  return __builtin_amdgcn_mfma_f32_16x16x32_bf16(a, b, c, 0, 0, 0);
}
// async global->LDS, 16B per lane; lds ptr wave-uniform base
__device__ __forceinline__ void gld16(const unsigned short* g, unsigned short* l) {
  __builtin_amdgcn_global_load_lds(
      (const __attribute__((address_space(1))) void*)g,
      (__attribute__((address_space(3))) void*)l, 16, 0, 0);
}

// ---- prep: count_k (blocks 0..31) | pack_wf (blocks 32..63) ---------------
__global__ __launch_bounds__(256) void prep_k(const float* __restrict__ W,
                                              const int* __restrict__ adj,
                                              unsigned short* __restrict__ Wf,
                                              int* __restrict__ kout) {
  const int bx = blockIdx.x, tid = threadIdx.x;
  if (bx < 32) {  // k = sum(adj[:,0] != 0)
    __shared__ int red[256];
    int gid = bx * 256 + tid;
    red[tid] = (adj[(size_t)gid * NN] != 0);
    __syncthreads();
    for (int off = 128; off; off >>= 1) {
      if (tid < off) red[tid] += red[tid + off];
      __syncthreads();
    }
    if (tid == 0) atomicAdd(kout, red[0]);
  } else {  // W -> bf16 B-frags
    int gid = (bx - 32) * 256 + tid;
    int l = gid & 63, f = gid >> 6, n16 = f >> 3, kk = f & 7;
    int lr = l & 15, lg = l >> 4;
    const float* src = W + (size_t)(n16 * 16 + lr) * DD + kk * 32 + lg * 8;
    float4 w0 = *(const float4*)src, w1 = *(const float4*)(src + 4);
    short8 o;
    o[0] = (short)f2bf(w0.x); o[1] = (short)f2bf(w0.y);
    o[2] = (short)f2bf(w0.z); o[3] = (short)f2bf(w0.w);
    o[4] = (short)f2bf(w1.x); o[5] = (short)f2bf(w1.y);
    o[6] = (short)f2bf(w1.z); o[7] = (short)f2bf(w1.w);
    *(short8*)(Wf + (size_t)gid * 8) = o;
  }
}

// ---- fused conv + h_new: h(f32) -> A-frags (regs) -> hQf store + GEMM -----
// 128 blocks x 4 waves x 16 rows. hnV stored with k-permutation
// perm(8*lg+e) = 4*lg + (e<4 ? e : e+12) to match swapped-QK P register order.
__global__ __launch_bounds__(256) void hnew_k(const float* __restrict__ h,
                                              const unsigned short* __restrict__ Wf,
                                              const float* __restrict__ bias,
                                              unsigned short* __restrict__ hQf,
                                              unsigned short* __restrict__ hnb,
                                              unsigned short* __restrict__ hnV) {
  const int tid = threadIdx.x, w = tid >> 6, l = tid & 63, lr = l & 15, lg = l >> 4;
  const int row0 = blockIdx.x * 64 + w * 16;
  const int j16 = row0 >> 4;

  short8 a[8];
#pragma unroll
  for (int kk = 0; kk < 8; ++kk) {  // convert own rows f32 -> bf16 frags
    const float* src = h + (size_t)(row0 + lr) * DD + kk * 32 + lg * 8;
    float4 v0 = *(const float4*)src, v1 = *(const float4*)(src + 4);
    short8 o;
    o[0] = (short)f2bf(v0.x); o[1] = (short)f2bf(v0.y);
    o[2] = (short)f2bf(v0.z); o[3] = (short)f2bf(v0.w);
    o[4] = (short)f2bf(v1.x); o[5] = (short)f2bf(v1.y);
    o[6] = (short)f2bf(v1.z); o[7] = (short)f2bf(v1.w);
    a[kk] = o;
    *(short8*)(hQf + ((size_t)(j16 * 8 + kk) * 64 + l) * 8) = o;  // K/Q frags
  }

  f32x4 acc[16];
#pragma unroll
  for (int nt = 0; nt < 16; ++nt) acc[nt] = (f32x4){0.f, 0.f, 0.f, 0.f};
#pragma unroll
  for (int kk = 0; kk < 8; ++kk)
#pragma unroll
    for (int nt = 0; nt < 16; ++nt) {
      short8 bf = *(const short8*)(Wf + ((size_t)(nt * 8 + kk) * 64 + l) * 8);
      acc[nt] = mfma16(a[kk], bf, acc[nt]);
    }
  const int rowbase = row0 + lg * 4;                // 4 rows, q contiguous
  const int eb = ((rowbase >> 4) & 1) * 4;          // permuted elem base
#pragma unroll
  for (int nt = 0; nt < 16; ++nt) {
    const int col = nt * 16 + lr;
    const float bv = bias[col];
    unsigned short r16[4];
#pragma unroll
    for (int q = 0; q < 4; ++q) r16[q] = f2bf(acc[nt][q] + bv);
#pragma unroll
    for (int q = 0; q < 4; ++q) hnb[(size_t)(rowbase + q) * DD + col] = r16[q];
    ushort4 o4 = {r16[0], r16[1], r16[2], r16[3]};
    // permuted V-frag: lane lg*16+lr, elems eb..eb+3 <- rows rowbase..+3
    *(ushort4*)(hnV + (((size_t)(rowbase >> 5) * 16 + nt) * 64 + lg * 16 + lr) * 8 +
                eb) = o4;
  }
}

// ---- flash attention partials: swapped QK^T, register-only P --------------
// Grid (S=16 chunks, 128 tiles of 64 rows): chunk%8 = XCD (L2-pinned K/V).
// 4 waves x 16 rows; dbuf LDS; 2x unrolled; 1 barrier/iter.
// S2 = mfma(Kfrag, Qfrag) -> lane (lg,lr) holds P[lr][nt*16+4lg+q]; PV A-frag
// pa[e] = (e<4) ? p[0][e] : p[1][e-4] matches hnV's permuted k-order.
__global__ __launch_bounds__(256, 2) void attn_k(
    const unsigned short* __restrict__ hQf, const unsigned short* __restrict__ hnV,
    const int* __restrict__ adj, const int* __restrict__ kptr,
    float* __restrict__ pl, unsigned short* __restrict__ pO, int T) {
  __shared__ __align__(16) unsigned short sK[2][8192];   // 16KB x2
  __shared__ __align__(16) unsigned short sV[2][8192];   // 16KB x2

  const int tid = threadIdx.x, w = tid >> 6, l = tid & 63, lr = l & 15, lg = l >> 4;
  const int c = blockIdx.x, ty = blockIdx.y;
  const int i0 = ty * 64;
  const int kid = *kptr;
  if (i0 + 64 <= kid) return;  // whole tile identity: comb_k handles it

  const int r0 = i0 + w * 16;  // this wave's 16 rows

  short8 qf[8];  // Q frags (used as B operand; same lane layout as A)
#pragma unroll
  for (int kk = 0; kk < 8; ++kk)
    qf[kk] = *(const short8*)(hQf + ((size_t)((r0 >> 4) * 8 + kk) * 64 + l) * 8);

  f32x4 Oacc[16];
#pragma unroll
  for (int nt = 0; nt < 16; ++nt) Oacc[nt] = (f32x4){0.f, 0.f, 0.f, 0.f};
  float lsum = 0.f;                       // all 8 p/iter belong to row lr
  const float c1 = 0.09016844005556021f;  // log2(e)/sqrt(256)

  const size_t arow = (size_t)(r0 + lr) * NN;  // this lane's mask row

  const int jt0 = c * T;

  // ---- prologue: stage tile jt0 into buf 0, masks into avA (int4 x2) ----
  {
    const unsigned short* srcK = hQf + (size_t)jt0 * 8192;
    const unsigned short* srcV = hnV + (size_t)jt0 * 8192;
#pragma unroll
    for (int s = 0; s < 4; ++s) {
      const int so = (w * 4 + s) * 512;
      gld16(srcK + so + l * 8, &sK[0][so]);
      gld16(srcV + so + l * 8, &sV[0][so]);
    }
  }
  int avA[8], avB[8];
  {
    int4 t0 = *(const int4*)(adj + arow + jt0 * 32 + lg * 4);
    int4 t1 = *(const int4*)(adj + arow + jt0 * 32 + 16 + lg * 4);
    avA[0] = t0.x; avA[1] = t0.y; avA[2] = t0.z; avA[3] = t0.w;
    avA[4] = t1.x; avA[5] = t1.y; avA[6] = t1.z; avA[7] = t1.w;
  }
  __syncthreads();

#define ATTN_ITER(T_IDX, CUR, MC, MN)                                          \
  {                                                                            \
    const int t_ = (T_IDX);                                                    \
    if (t_ + 1 < T) { /* stage next tile + next masks */                       \
      const int jn = jt0 + t_ + 1;                                             \
      const unsigned short* srcK = hQf + (size_t)jn * 8192;                    \
      const unsigned short* srcV = hnV + (size_t)jn * 8192;                    \
      _Pragma("unroll") for (int s = 0; s < 4; ++s) {                          \
        const int so = (w * 4 + s) * 512;                                      \
        gld16(srcK + so + l * 8, &sK[(CUR) ^ 1][so]);                          \
        gld16(srcV + so + l * 8, &sV[(CUR) ^ 1][so]);                          \
      }                                                                        \
      int4 t0 = *(const int4*)(adj + arow + jn * 32 + lg * 4);                 \
      int4 t1 = *(const int4*)(adj + arow + jn * 32 + 16 + lg * 4);            \
      MN[0] = t0.x; MN[1] = t0.y; MN[2] = t0.z; MN[3] = t0.w;                  \
      MN[4] = t1.x; MN[5] = t1.y; MN[6] = t1.z; MN[7] = t1.w;                  \
    }                                                                          \
    f32x4 S2[2];                                                               \
    S2[0] = (f32x4){0.f, 0.f, 0.f, 0.f};                                       \
    S2[1] = (f32x4){0.f, 0.f, 0.f, 0.f};                                       \
    __builtin_amdgcn_s_setprio(1);                                             \
    _Pragma("unroll") for (int kk = 0; kk < 8; ++kk)                           \
      _Pragma("unroll") for (int nt = 0; nt < 2; ++nt) {                       \
        short8 kf = *(const short8*)(&sK[(CUR)][(nt * 8 + kk) * 512 + l * 8]); \
        S2[nt] = mfma16(kf, qf[kk], S2[nt]); /* swapped: S^T */                \
      }                                                                        \
    __builtin_amdgcn_s_setprio(0);                                             \
    float p[2][4];                                                             \
    _Pragma("unroll") for (int nt = 0; nt < 2; ++nt)                           \
      _Pragma("unroll") for (int q = 0; q < 4; ++q) {                          \
        float sv = MC[nt * 4 + q] ? fminf(S2[nt][q] * c1, 60.f) : NEGB;        \
        p[nt][q] = __builtin_amdgcn_exp2f(sv);                                 \
      }                                                                        \
    lsum += ((p[0][0] + p[0][1]) + (p[0][2] + p[0][3])) +                      \
            ((p[1][0] + p[1][1]) + (p[1][2] + p[1][3]));                       \
    short8 pa;                                                                 \
    _Pragma("unroll") for (int e = 0; e < 4; ++e) {                            \
      pa[e] = (short)f2bf(p[0][e]);                                            \
      pa[e + 4] = (short)f2bf(p[1][e]);                                        \
    }                                                                          \
    __builtin_amdgcn_s_setprio(1);                                             \
    _Pragma("unroll") for (int cnt = 0; cnt < 16; ++cnt) {                     \
      short8 vf = *(const short8*)(&sV[(CUR)][cnt * 512 + l * 8]);             \
      Oacc[cnt] = mfma16(pa, vf, Oacc[cnt]);                                   \
    }                                                                          \
    __builtin_amdgcn_s_setprio(0);                                             \
    __syncthreads();                                                           \
  }

  for (int tt = 0; tt < T; tt += 2) {
    ATTN_ITER(tt, 0, avA, avB);      // compute buf0/avA, stage buf1/avB
    ATTN_ITER(tt + 1, 1, avB, avA);  // compute buf1/avB, stage buf0/avA
  }
#undef ATTN_ITER

  // ---- reduce denominators across lg (shfl 16,32), write partials ----
  lsum += __shfl_xor(lsum, 16);
  lsum += __shfl_xor(lsum, 32);
  if (lg == 0) pl[(size_t)c * NN + r0 + lr] = lsum;
#pragma unroll
  for (int cnt = 0; cnt < 16; ++cnt)
#pragma unroll
    for (int q = 0; q < 4; ++q) {
      int row = r0 + lg * 4 + q;
      pO[((size_t)c * NN + row) * DD + cnt * 16 + lr] = f2bf(Oacc[cnt][q]);
    }
}

// ---- combine chunks + epilogue: 4 rows/block, ushort4 lanes ---------------
__global__ __launch_bounds__(256) void comb_k(const float* __restrict__ pl,
                                              const unsigned short* __restrict__ pO,
                                              const unsigned short* __restrict__ hnb,
                                              const int* __restrict__ kptr,
                                              float* __restrict__ out, int S) {
  const int row = blockIdx.x * 4 + (threadIdx.x >> 6);
  const int col = (threadIdx.x & 63) * 4;
  const int kid = *kptr;
  ushort4 hv = *(const ushort4*)(hnb + (size_t)row * DD + col);
  float v0 = bf2f(hv.x), v1 = bf2f(hv.y), v2 = bf2f(hv.z), v3 = bf2f(hv.w);
  float4 r;
  if (row < kid) {
    r.x = v0; r.y = v1; r.z = v2; r.w = v3;
  } else {
    float L = 0.f, a0 = 0.f, a1 = 0.f, a2 = 0.f, a3 = 0.f;
    for (int cc = 0; cc < S; ++cc) {
      L += pl[(size_t)cc * NN + row];
      ushort4 ov = *(const ushort4*)(pO + ((size_t)cc * NN + row) * DD + col);
      a0 += bf2f(ov.x); a1 += bf2f(ov.y); a2 += bf2f(ov.z); a3 += bf2f(ov.w);
    }
    float inv = 0.5f / L;
    r.x = a0 * inv + 0.5f * v0; r.y = a1 * inv + 0.5f * v1;
    r.z = a2 * inv + 0.5f * v2; r.w = a3 * inv + 0.5f * v3;
  }
  r.x = fmaxf(r.x, 0.f); r.y = fmaxf(r.y, 0.f);
  r.z = fmaxf(r.z, 0.f); r.w = fmaxf(r.w, 0.f);
  *(float4*)(out + (size_t)row * DD + col) = r;
}

extern "C" void kernel_launch(void* const* d_in, const int* in_sizes, int n_in,
                              void* d_out, int out_size, void* d_ws, size_t ws_size,
                              hipStream_t stream) {
  const float* h = (const float*)d_in[0];
  const int* adj = (const int*)d_in[1];
  const float* W = (const float*)d_in[2];
  const float* b = (const float*)d_in[3];
  float* out = (float*)d_out;

  char* ws = (char*)d_ws;
  const size_t MB4 = (size_t)NN * DD * 2;  // 4 MiB
  int* kbuf = (int*)ws;
  unsigned short* hQf = (unsigned short*)(ws + 256);
  unsigned short* hnb = (unsigned short*)(ws + 256 + MB4);
  unsigned short* hnV = (unsigned short*)(ws + 256 + 2 * MB4);
  unsigned short* Wf = (unsigned short*)(ws + 256 + 3 * MB4);  // 128 KiB
  char* dyn = ws + 256 + 3 * MB4 + (256 << 10);

  size_t fixed = 256 + 3 * MB4 + (256 << 10);
  int S = 16;
  while (S > 1 && fixed + (size_t)S * NN * (DD * 2 + 4) > ws_size) S >>= 1;
  const int T = 256 / S;

  float* pl = (float*)dyn;
  unsigned short* pO = (unsigned short*)(pl + (size_t)S * NN);

  hipMemsetAsync(kbuf, 0, 4, stream);
  hipLaunchKernelGGL(prep_k, dim3(64), dim3(256), 0, stream, W, adj, Wf, kbuf);
  hipLaunchKernelGGL(hnew_k, dim3(NN / 64), dim3(256), 0, stream,
                     h, Wf, b, hQf, hnb, hnV);
  hipLaunchKernelGGL(attn_k, dim3(S, NN / 64), dim3(256), 0, stream,
                     hQf, hnV, adj, kbuf, pl, pO, T);
  hipLaunchKernelGGL(comb_k, dim3(NN / 4), dim3(256), 0, stream, pl, pO, hnb, kbuf, out, S);
}